// Round 2
// baseline (3748.284 us; speedup 1.0000x reference)
//
#include <hip/hip_runtime.h>

#define NN 100000
#define NE 1600000
#define NT 12500     // NE / 128 edge tiles
#define EGRID 768    // persistent blocks (3 per CU)

typedef short s8v __attribute__((ext_vector_type(8)));
typedef float f32x4 __attribute__((ext_vector_type(4)));
typedef unsigned short u16;

__device__ __forceinline__ u16 f2bf(float f) {
    union { float f; unsigned u; } v; v.f = f;
    unsigned r = v.u + 0x7FFFu + ((v.u >> 16) & 1u);
    return (u16)(r >> 16);
}
__device__ __forceinline__ unsigned pk2(float a, float b) {
    return (unsigned)f2bf(a) | ((unsigned)f2bf(b) << 16);
}

// ---------------- weight fragment packing (bf16, B-operand layout) -------------
__global__ void pack_weights(const float* __restrict__ pW,
                             const float* __restrict__ eW1, const float* __restrict__ eW2,
                             const float* __restrict__ nW1, const float* __restrict__ nW2,
                             u16* __restrict__ wpack) {
    int b = blockIdx.x, L = threadIdx.x;
    const float* src; int s, t;
    if (b < 16) { src = pW; s = b >> 2; t = b & 3; }
    else {
        int bb = b - 16, l = bb / 56, r = bb % 56;
        if (r < 24)      {            src = eW1 + l*192*64; s = r>>2; t = r&3; }
        else if (r < 32) { r -= 24;   src = eW2 + l*64*64;  s = r>>2; t = r&3; }
        else if (r < 48) { r -= 32;   src = nW1 + l*128*64; s = r>>2; t = r&3; }
        else             { r -= 48;   src = nW2 + l*64*64;  s = r>>2; t = r&3; }
    }
    int kbase = s*32 + (L>>4)*8;
    int n = t*16 + (L&15);
    u16* dst = wpack + (size_t)b*512 + (size_t)L*8;
#pragma unroll
    for (int j = 0; j < 8; ++j) dst[j] = f2bf(src[(kbase+j)*64 + n]);
}

// ---------------- edge_attr fp32 -> bf16 (one pass, keeps hot kernel uniform) --
__global__ void cvt_ea(const float* __restrict__ src, u16* __restrict__ dst) {
    size_t i = ((size_t)blockIdx.x * 256 + threadIdx.x) * 8;
    float4 a = *(const float4*)(src + i);
    float4 b = *(const float4*)(src + i + 4);
    uint4 v;
    v.x = pk2(a.x, a.y); v.y = pk2(a.z, a.w);
    v.z = pk2(b.x, b.y); v.w = pk2(b.z, b.w);
    *(uint4*)(dst + i) = v;
}

// ---------------- node projection: h = x @ pW + pb (bf16 MFMA) -----------------
__global__ __launch_bounds__(256) void node_proj(const float* __restrict__ x,
                                                 const float* __restrict__ pb,
                                                 const u16* __restrict__ wpack,
                                                 float* __restrict__ h,
                                                 u16* __restrict__ h_bf) {
    __shared__ __align__(16) u16 sX[64*136];
    const int tid = threadIdx.x;
    const int n0 = blockIdx.x * 64;
    for (int i = tid; i < 64*32; i += 256) {
        int node = i >> 5, c = i & 31;
        float4 v = make_float4(0.f, 0.f, 0.f, 0.f);
        if (n0 + node < NN) v = *(const float4*)(x + (size_t)(n0+node)*128 + c*4);
        *(uint2*)&sX[node*136 + c*4] = make_uint2(pk2(v.x, v.y), pk2(v.z, v.w));
    }
    __syncthreads();
    const int w = tid >> 6, L = tid & 63;
    const int m = L & 15, kc = L >> 4;
    const int wb = w * 16;
    const f32x4 z = {0.f, 0.f, 0.f, 0.f};
    f32x4 acc[4] = {z, z, z, z};
#pragma unroll
    for (int s = 0; s < 4; ++s) {
        s8v a = *(const s8v*)&sX[(wb+m)*136 + s*32 + kc*8];
#pragma unroll
        for (int t = 0; t < 4; ++t) {
            s8v bf = *(const s8v*)(wpack + ((size_t)(s*4+t)*64 + L)*8);
            acc[t] = __builtin_amdgcn_mfma_f32_16x16x32_bf16(a, bf, acc[t], 0, 0, 0);
        }
    }
#pragma unroll
    for (int t = 0; t < 4; ++t) {
        int u = t*16 + m;
        float bias = pb[u];
#pragma unroll
        for (int r = 0; r < 4; ++r) {
            int node = n0 + wb + kc*4 + r;
            if (node < NN) {
                float v = acc[t][r] + bias;
                h[(size_t)node*64 + u] = v;
                h_bf[(size_t)node*64 + u] = f2bf(v);
            }
        }
    }
}

// ---------------- fused per-layer edge kernel (persistent, pipelined) ----------
// 768 blocks x 256 thr; grid-stride over 12500 tiles of 128 edges.
// Staging: thread = (edge e = tid>>1, half = tid&1); 2 idx loads + 12 branchless
// uint4 gathers into registers (prefetched one tile ahead), 12 ds_write_b128.
// Compute: wave-private 32 rows; t1/t2 alias the dead h_col LDS slot -> 52 KB LDS.
__global__ __launch_bounds__(256, 3) void edge_layer(const int* __restrict__ ei,
                                                     const u16* __restrict__ h_bf,
                                                     u16* __restrict__ ea_bf,
                                                     const u16* __restrict__ wp,
                                                     const float* __restrict__ eb1,
                                                     const float* __restrict__ eb2,
                                                     const float* __restrict__ nb1,
                                                     const float* __restrict__ nb2,
                                                     float* __restrict__ agg) {
    __shared__ __align__(16) u16 sAct[128*200];   // [h_row(64)|t1/t2 over h_col(64)|ea(64)]
    __shared__ int sCol[128];
    const int tid = threadIdx.x;
    const int e = tid >> 1, half = tid & 1;
    const int sBase = e*200 + half*96;
    const int w = tid >> 6, L = tid & 63;
    const int m = L & 15, kc = L >> 4;
    const int wb = w * 32;
    float be1[4], be2[4], bn1[4], bn2[4];
#pragma unroll
    for (int t = 0; t < 4; ++t) {
        int u = t*16 + m;
        be1[t] = eb1[u]; be2[t] = eb2[u]; bn1[t] = nb1[u]; bn2[t] = nb2[u];
    }
    const f32x4 z = {0.f, 0.f, 0.f, 0.f};

    uint4 rbuf[12];
    int rCol;
    {   // prefetch tile = blockIdx.x
        int t0 = blockIdx.x;
        int row = ei[t0*128 + e];
        int col = ei[(size_t)NE + t0*128 + e];
        rCol = col;
        const u16* hr = h_bf + (size_t)row*64;
        const u16* hc = h_bf + (size_t)col*64;
        const u16* ep = ea_bf + ((size_t)t0*128 + e)*64;
#pragma unroll
        for (int j = 0; j < 4;  ++j) rbuf[j] = *(const uint4*)(half ? hc + (4+j)*8 : hr + j*8);
#pragma unroll
        for (int j = 4; j < 8;  ++j) rbuf[j] = *(const uint4*)(half ? ep + (j-4)*8 : hr + j*8);
#pragma unroll
        for (int j = 8; j < 12; ++j) rbuf[j] = *(const uint4*)(half ? ep + (j-4)*8 : hc + (j-8)*8);
    }

    for (int tile = blockIdx.x; tile < NT; tile += EGRID) {
        const int next = tile + EGRID;
        __syncthreads();                       // prev compute done; LDS free; prefetch drained
        if (!half) sCol[e] = rCol;
#pragma unroll
        for (int j = 0; j < 12; ++j) *(uint4*)&sAct[sBase + j*8] = rbuf[j];
        int nRow = 0, nCol = 0;
        if (next < NT) {
            nRow = ei[next*128 + e];
            nCol = ei[(size_t)NE + next*128 + e];
        }
        __syncthreads();                       // staging visible

        f32x4 acc[2][4];
        // ---- GEMM1: ein[*,192] @ eW1 ----
#pragma unroll
        for (int g = 0; g < 2; ++g)
#pragma unroll
            for (int t = 0; t < 4; ++t) acc[g][t] = z;
#pragma unroll
        for (int s = 0; s < 6; ++s) {
            s8v a0 = *(const s8v*)&sAct[(wb + m)*200 + s*32 + kc*8];
            s8v a1 = *(const s8v*)&sAct[(wb + 16 + m)*200 + s*32 + kc*8];
#pragma unroll
            for (int t = 0; t < 4; ++t) {
                s8v bf = *(const s8v*)(wp + ((size_t)(s*4+t)*64 + L)*8);
                acc[0][t] = __builtin_amdgcn_mfma_f32_16x16x32_bf16(a0, bf, acc[0][t], 0, 0, 0);
                acc[1][t] = __builtin_amdgcn_mfma_f32_16x16x32_bf16(a1, bf, acc[1][t], 0, 0, 0);
            }
        }
        // ---- issue next tile's gathers (overlap with GEMM2-4) ----
        if (next < NT) {
            const u16* hr = h_bf + (size_t)nRow*64;
            const u16* hc = h_bf + (size_t)nCol*64;
            const u16* ep = ea_bf + ((size_t)next*128 + e)*64;
#pragma unroll
            for (int j = 0; j < 4;  ++j) rbuf[j] = *(const uint4*)(half ? hc + (4+j)*8 : hr + j*8);
#pragma unroll
            for (int j = 4; j < 8;  ++j) rbuf[j] = *(const uint4*)(half ? ep + (j-4)*8 : hr + j*8);
#pragma unroll
            for (int j = 8; j < 12; ++j) rbuf[j] = *(const uint4*)(half ? ep + (j-4)*8 : hc + (j-8)*8);
            rCol = nCol;
        }
        // ---- GEMM1 epilogue: relu -> t1 into h_col slot (wave-private rows) ----
#pragma unroll
        for (int g = 0; g < 2; ++g)
#pragma unroll
            for (int t = 0; t < 4; ++t) {
                int u = t*16 + m;
#pragma unroll
                for (int r = 0; r < 4; ++r) {
                    float v = acc[g][t][r] + be1[t];
                    v = v > 0.f ? v : 0.f;
                    sAct[(wb + g*16 + kc*4 + r)*200 + 64 + u] = f2bf(v);
                }
            }

        // ---- GEMM2: t1 @ eW2 -> ea_new ----
        const u16* wp2 = wp + 24*512;
#pragma unroll
        for (int g = 0; g < 2; ++g)
#pragma unroll
            for (int t = 0; t < 4; ++t) acc[g][t] = z;
#pragma unroll
        for (int s = 0; s < 2; ++s) {
            s8v a0 = *(const s8v*)&sAct[(wb + m)*200 + 64 + s*32 + kc*8];
            s8v a1 = *(const s8v*)&sAct[(wb + 16 + m)*200 + 64 + s*32 + kc*8];
#pragma unroll
            for (int t = 0; t < 4; ++t) {
                s8v bf = *(const s8v*)(wp2 + ((size_t)(s*4+t)*64 + L)*8);
                acc[0][t] = __builtin_amdgcn_mfma_f32_16x16x32_bf16(a0, bf, acc[0][t], 0, 0, 0);
                acc[1][t] = __builtin_amdgcn_mfma_f32_16x16x32_bf16(a1, bf, acc[1][t], 0, 0, 0);
            }
        }
#pragma unroll
        for (int g = 0; g < 2; ++g)
#pragma unroll
            for (int t = 0; t < 4; ++t) {
                int u = t*16 + m;
#pragma unroll
                for (int r = 0; r < 4; ++r) {
                    float v = acc[g][t][r] + be2[t];
                    u16 bv = f2bf(v);
                    int er = wb + g*16 + kc*4 + r;
                    sAct[er*200 + 128 + u] = bv;                       // new ea (own rows)
                    ea_bf[((size_t)tile*128 + er)*64 + u] = bv;        // persist for next layer
                }
            }

        // ---- GEMM3: [h_row|ea_new][*,128] @ nW1 ----
        const u16* wp3 = wp + 32*512;
#pragma unroll
        for (int g = 0; g < 2; ++g)
#pragma unroll
            for (int t = 0; t < 4; ++t) acc[g][t] = z;
#pragma unroll
        for (int s = 0; s < 4; ++s) {
            int c = s*4 + kc;
            int off = c*8 + (c >= 8 ? 64 : 0);    // skip t1/t2 slot
            s8v a0 = *(const s8v*)&sAct[(wb + m)*200 + off];
            s8v a1 = *(const s8v*)&sAct[(wb + 16 + m)*200 + off];
#pragma unroll
            for (int t = 0; t < 4; ++t) {
                s8v bf = *(const s8v*)(wp3 + ((size_t)(s*4+t)*64 + L)*8);
                acc[0][t] = __builtin_amdgcn_mfma_f32_16x16x32_bf16(a0, bf, acc[0][t], 0, 0, 0);
                acc[1][t] = __builtin_amdgcn_mfma_f32_16x16x32_bf16(a1, bf, acc[1][t], 0, 0, 0);
            }
        }
#pragma unroll
        for (int g = 0; g < 2; ++g)
#pragma unroll
            for (int t = 0; t < 4; ++t) {
                int u = t*16 + m;
#pragma unroll
                for (int r = 0; r < 4; ++r) {
                    float v = acc[g][t][r] + bn1[t];
                    v = v > 0.f ? v : 0.f;
                    sAct[(wb + g*16 + kc*4 + r)*200 + 64 + u] = f2bf(v);  // t2
                }
            }

        // ---- GEMM4: t2 @ nW2 -> msg; scatter-add ----
        const u16* wp4 = wp + 48*512;
#pragma unroll
        for (int g = 0; g < 2; ++g)
#pragma unroll
            for (int t = 0; t < 4; ++t) acc[g][t] = z;
#pragma unroll
        for (int s = 0; s < 2; ++s) {
            s8v a0 = *(const s8v*)&sAct[(wb + m)*200 + 64 + s*32 + kc*8];
            s8v a1 = *(const s8v*)&sAct[(wb + 16 + m)*200 + 64 + s*32 + kc*8];
#pragma unroll
            for (int t = 0; t < 4; ++t) {
                s8v bf = *(const s8v*)(wp4 + ((size_t)(s*4+t)*64 + L)*8);
                acc[0][t] = __builtin_amdgcn_mfma_f32_16x16x32_bf16(a0, bf, acc[0][t], 0, 0, 0);
                acc[1][t] = __builtin_amdgcn_mfma_f32_16x16x32_bf16(a1, bf, acc[1][t], 0, 0, 0);
            }
        }
#pragma unroll
        for (int g = 0; g < 2; ++g)
#pragma unroll
            for (int t = 0; t < 4; ++t) {
                int u = t*16 + m;
#pragma unroll
                for (int r = 0; r < 4; ++r) {
                    int er = wb + g*16 + kc*4 + r;
                    unsafeAtomicAdd(&agg[(size_t)sCol[er]*64 + u], acc[g][t][r] + bn2[t]);
                }
            }
    }
}

// ---------------- h = relu(agg + h); refresh bf16 copy; re-zero agg ------------
__global__ void update_h(float* __restrict__ h, float* __restrict__ agg,
                         u16* __restrict__ h_bf, int zero_agg) {
    int i = (blockIdx.x * 256 + threadIdx.x) * 4;
    float4 a = *(const float4*)(agg + i);
    float4 hv = *(const float4*)(h + i);
    float4 v;
    v.x = fmaxf(a.x + hv.x, 0.f);
    v.y = fmaxf(a.y + hv.y, 0.f);
    v.z = fmaxf(a.z + hv.z, 0.f);
    v.w = fmaxf(a.w + hv.w, 0.f);
    *(float4*)(h + i) = v;
    *(uint2*)(h_bf + i) = make_uint2(pk2(v.x, v.y), pk2(v.z, v.w));
    if (zero_agg) *(float4*)(agg + i) = make_float4(0.f, 0.f, 0.f, 0.f);
}

// ---------------- mean pool ----------------------------------------------------
__global__ void pool1(const float* __restrict__ h, float* __restrict__ pooled) {
    float acc = 0.f;
    const int stride = gridDim.x * 256;
    for (int i = blockIdx.x * 256 + threadIdx.x; i < NN*64; i += stride)
        acc += h[i];
    __shared__ float sp[256];
    sp[threadIdx.x] = acc;
    __syncthreads();
    if (threadIdx.x < 64) {
        float v = sp[threadIdx.x] + sp[threadIdx.x+64] + sp[threadIdx.x+128] + sp[threadIdx.x+192];
        unsafeAtomicAdd(&pooled[threadIdx.x], v);
    }
}

__global__ void pool2(const float* __restrict__ pooled, const float* __restrict__ lW,
                      const float* __restrict__ lb, float* __restrict__ out) {
    int k = threadIdx.x;   // 64 threads
    float v = pooled[k] * (1.0f / NN);
#pragma unroll
    for (int o = 0; o < 3; ++o) {
        float p = v * lW[k*3 + o];
        for (int off = 32; off > 0; off >>= 1)
            p += __shfl_down(p, off);
        if (k == 0) out[o] = p + lb[o];
    }
}

extern "C" void kernel_launch(void* const* d_in, const int* in_sizes, int n_in,
                              void* d_out, int out_size, void* d_ws, size_t ws_size,
                              hipStream_t stream) {
    const float* x         = (const float*)d_in[0];
    const int*   ei        = (const int*)d_in[1];
    const float* edge_attr = (const float*)d_in[2];
    const float* pW        = (const float*)d_in[3];
    const float* pb        = (const float*)d_in[4];
    const float* eW1       = (const float*)d_in[5];
    const float* eb1       = (const float*)d_in[6];
    const float* eW2       = (const float*)d_in[7];
    const float* eb2       = (const float*)d_in[8];
    const float* nW1       = (const float*)d_in[9];
    const float* nb1       = (const float*)d_in[10];
    const float* nW2       = (const float*)d_in[11];
    const float* nb2       = (const float*)d_in[12];
    const float* lW        = (const float*)d_in[13];
    const float* lb        = (const float*)d_in[14];
    float* out = (float*)d_out;

    char* ws = (char*)d_ws;
    float* h     = (float*)(ws);                         // 25,600,000 B
    float* agg   = (float*)(ws + 25600000);              // 25,600,000 B
    u16*   h_bf  = (u16*)  (ws + 51200000);              // 12,800,000 B
    u16*   ea_bf = (u16*)  (ws + 64000000);              // 204,800,000 B
    u16*   wpack = (u16*)  (ws + 268800000);             // 188,416 B
    float* pooled= (float*)(ws + 268988416);             // 256 B

    pack_weights<<<184, 64, 0, stream>>>(pW, eW1, eW2, nW1, nW2, wpack);
    node_proj<<<(NN + 63)/64, 256, 0, stream>>>(x, pb, wpack, h, h_bf);
    cvt_ea<<<NE*64/(8*256), 256, 0, stream>>>(edge_attr, ea_bf);
    hipMemsetAsync(agg, 0, (size_t)NN*64*4, stream);
    for (int l = 0; l < 3; ++l) {
        edge_layer<<<EGRID, 256, 0, stream>>>(ei, h_bf, ea_bf,
                                              wpack + (16 + l*56)*512,
                                              eb1 + l*64, eb2 + l*64, nb1 + l*64, nb2 + l*64,
                                              agg);
        update_h<<<NN*64/4/256, 256, 0, stream>>>(h, agg, h_bf, l < 2 ? 1 : 0);
    }
    hipMemsetAsync(pooled, 0, 64*4, stream);
    pool1<<<256, 256, 0, stream>>>(h, pooled);
    pool2<<<1, 64, 0, stream>>>(pooled, lW, lb, out);
}

// Round 3
// 1951.652 us; speedup vs baseline: 1.9206x; 1.9206x over previous
//
#include <hip/hip_runtime.h>

#define NN 100000
#define NE 1600000

typedef short s8v __attribute__((ext_vector_type(8)));
typedef float f32x4 __attribute__((ext_vector_type(4)));
typedef unsigned short u16;

__device__ __forceinline__ u16 f2bf(float f) {
    union { float f; unsigned u; } v; v.f = f;
    unsigned r = v.u + 0x7FFFu + ((v.u >> 16) & 1u);
    return (u16)(r >> 16);
}
__device__ __forceinline__ unsigned pk2(float a, float b) {
    return (unsigned)f2bf(a) | ((unsigned)f2bf(b) << 16);
}

// ---------------- weight fragment packing (bf16, B-operand layout) -------------
// frag f at wpack + f*512: lane L holds 8 bf16 = B[k = s*32+(L>>4)*8+j][n = t*16+(L&15)]
// order: pW (16) | per layer: eW1 (24) eW2 (8) nW1 (16) nW2 (8)
__global__ void pack_weights(const float* __restrict__ pW,
                             const float* __restrict__ eW1, const float* __restrict__ eW2,
                             const float* __restrict__ nW1, const float* __restrict__ nW2,
                             u16* __restrict__ wpack) {
    int b = blockIdx.x, L = threadIdx.x;
    const float* src; int s, t;
    if (b < 16) { src = pW; s = b >> 2; t = b & 3; }
    else {
        int bb = b - 16, l = bb / 56, r = bb % 56;
        if (r < 24)      {            src = eW1 + l*192*64; s = r>>2; t = r&3; }
        else if (r < 32) { r -= 24;   src = eW2 + l*64*64;  s = r>>2; t = r&3; }
        else if (r < 48) { r -= 32;   src = nW1 + l*128*64; s = r>>2; t = r&3; }
        else             { r -= 48;   src = nW2 + l*64*64;  s = r>>2; t = r&3; }
    }
    int kbase = s*32 + (L>>4)*8;
    int n = t*16 + (L&15);
    u16* dst = wpack + (size_t)b*512 + (size_t)L*8;
#pragma unroll
    for (int j = 0; j < 8; ++j) dst[j] = f2bf(src[(kbase+j)*64 + n]);
}

// ---------------- edge_attr fp32 -> bf16 ---------------------------------------
__global__ void cvt_ea(const float* __restrict__ src, u16* __restrict__ dst) {
    size_t i = ((size_t)blockIdx.x * 256 + threadIdx.x) * 8;
    float4 a = *(const float4*)(src + i);
    float4 b = *(const float4*)(src + i + 4);
    uint4 v;
    v.x = pk2(a.x, a.y); v.y = pk2(a.z, a.w);
    v.z = pk2(b.x, b.y); v.w = pk2(b.z, b.w);
    *(uint4*)(dst + i) = v;
}

// ---------------- node projection: h = x @ pW + pb -----------------------------
__global__ __launch_bounds__(256) void node_proj(const float* __restrict__ x,
                                                 const float* __restrict__ pb,
                                                 const u16* __restrict__ wpack,
                                                 float* __restrict__ h,
                                                 u16* __restrict__ h_bf) {
    __shared__ __align__(16) u16 sX[64*136];
    const int tid = threadIdx.x;
    const int n0 = blockIdx.x * 64;
    for (int i = tid; i < 64*32; i += 256) {
        int node = i >> 5, c = i & 31;
        float4 v = make_float4(0.f, 0.f, 0.f, 0.f);
        if (n0 + node < NN) v = *(const float4*)(x + (size_t)(n0+node)*128 + c*4);
        *(uint2*)&sX[node*136 + c*4] = make_uint2(pk2(v.x, v.y), pk2(v.z, v.w));
    }
    __syncthreads();
    const int w = tid >> 6, L = tid & 63;
    const int m = L & 15, kc = L >> 4;
    const int wb = w * 16;
    const f32x4 z = {0.f, 0.f, 0.f, 0.f};
    f32x4 acc[4] = {z, z, z, z};
#pragma unroll
    for (int s = 0; s < 4; ++s) {
        s8v a = *(const s8v*)&sX[(wb+m)*136 + s*32 + kc*8];
#pragma unroll
        for (int t = 0; t < 4; ++t) {
            s8v bf = *(const s8v*)(wpack + ((size_t)(s*4+t)*64 + L)*8);
            acc[t] = __builtin_amdgcn_mfma_f32_16x16x32_bf16(a, bf, acc[t], 0, 0, 0);
        }
    }
#pragma unroll
    for (int t = 0; t < 4; ++t) {
        int u = t*16 + m;
        float bias = pb[u];
#pragma unroll
        for (int r = 0; r < 4; ++r) {
            int node = n0 + wb + kc*4 + r;
            if (node < NN) {
                float v = acc[t][r] + bias;
                h[(size_t)node*64 + u] = v;
                h_bf[(size_t)node*64 + u] = f2bf(v);
            }
        }
    }
}

// ---------------- fused per-layer edge kernel (barrier-free) -------------------
// 256 thr / 4 waves; each wave owns 32 edges, fully independent (no __syncthreads).
// MFMA A-operands (h_row / h_col / ea) are loaded DIRECTLY from global in
// fragment order (lane = 16B contiguous; s-pairs cover full 128B lines).
// LDS only holds the wave-private C->A transposes (t1 / ea_new / t2): 34.8 KB
// -> 4 blocks/CU = 16 waves/CU.
__global__ __launch_bounds__(256, 4) void edge_layer(const int* __restrict__ ei,
                                                     const u16* __restrict__ h_bf,
                                                     u16* __restrict__ ea_bf,
                                                     const u16* __restrict__ wp,
                                                     const float* __restrict__ eb1,
                                                     const float* __restrict__ eb2,
                                                     const float* __restrict__ nb1,
                                                     const float* __restrict__ nb2,
                                                     float* __restrict__ agg) {
    __shared__ __align__(16) u16 sB[4*32*136];   // per-wave 32 rows x [t(64)|ea(64)|pad 8]
    const int tid = threadIdx.x;
    const int w = tid >> 6, L = tid & 63;
    const int m = L & 15, kc = L >> 4;
    const int wb = w * 32;
    const size_t e0 = (size_t)blockIdx.x * 128;
    u16* sW = sB + w * 32 * 136;

    float be1[4], be2[4], bn1[4], bn2[4];
#pragma unroll
    for (int t = 0; t < 4; ++t) {
        int u = t*16 + m;
        be1[t] = eb1[u]; be2[t] = eb2[u]; bn1[t] = nb1[u]; bn2[t] = nb2[u];
    }
    int rowI[2];
#pragma unroll
    for (int g = 0; g < 2; ++g) rowI[g] = ei[e0 + wb + g*16 + m];
    int colI[2];
#pragma unroll
    for (int g = 0; g < 2; ++g) colI[g] = ei[(size_t)NE + e0 + wb + g*16 + m];

    const f32x4 z = {0.f, 0.f, 0.f, 0.f};
    f32x4 acc[2][4];

    // ---- GEMM1: [h_row|h_col|ea][*,192] @ eW1 (A direct from global) ----
#pragma unroll
    for (int g = 0; g < 2; ++g)
#pragma unroll
        for (int t = 0; t < 4; ++t) acc[g][t] = z;
#pragma unroll
    for (int s = 0; s < 6; ++s) {
        s8v a[2];
#pragma unroll
        for (int g = 0; g < 2; ++g) {
            if (s < 2)
                a[g] = *(const s8v*)(h_bf + (size_t)rowI[g]*64 + s*32 + kc*8);
            else if (s < 4)
                a[g] = *(const s8v*)(h_bf + (size_t)colI[g]*64 + (s-2)*32 + kc*8);
            else
                a[g] = *(const s8v*)(ea_bf + (e0 + wb + g*16 + m)*64 + (s-4)*32 + kc*8);
        }
#pragma unroll
        for (int t = 0; t < 4; ++t) {
            s8v bf = *(const s8v*)(wp + ((size_t)(s*4+t)*64 + L)*8);
            acc[0][t] = __builtin_amdgcn_mfma_f32_16x16x32_bf16(a[0], bf, acc[0][t], 0, 0, 0);
            acc[1][t] = __builtin_amdgcn_mfma_f32_16x16x32_bf16(a[1], bf, acc[1][t], 0, 0, 0);
        }
    }
    // relu -> t1 into LDS cols 0..63 (wave-private)
#pragma unroll
    for (int g = 0; g < 2; ++g)
#pragma unroll
        for (int t = 0; t < 4; ++t) {
            int u = t*16 + m;
#pragma unroll
            for (int r = 0; r < 4; ++r) {
                float v = acc[g][t][r] + be1[t];
                v = v > 0.f ? v : 0.f;
                sW[(g*16 + kc*4 + r)*136 + u] = f2bf(v);
            }
        }

    // ---- GEMM2: t1 @ eW2 -> ea_new ----
    const u16* wp2 = wp + 24*512;
#pragma unroll
    for (int g = 0; g < 2; ++g)
#pragma unroll
        for (int t = 0; t < 4; ++t) acc[g][t] = z;
#pragma unroll
    for (int s = 0; s < 2; ++s) {
        s8v a0 = *(const s8v*)&sW[(m)*136 + s*32 + kc*8];
        s8v a1 = *(const s8v*)&sW[(16 + m)*136 + s*32 + kc*8];
#pragma unroll
        for (int t = 0; t < 4; ++t) {
            s8v bf = *(const s8v*)(wp2 + ((size_t)(s*4+t)*64 + L)*8);
            acc[0][t] = __builtin_amdgcn_mfma_f32_16x16x32_bf16(a0, bf, acc[0][t], 0, 0, 0);
            acc[1][t] = __builtin_amdgcn_mfma_f32_16x16x32_bf16(a1, bf, acc[1][t], 0, 0, 0);
        }
    }
    // ea_new (+bias, no relu) -> LDS cols 64..127
#pragma unroll
    for (int g = 0; g < 2; ++g)
#pragma unroll
        for (int t = 0; t < 4; ++t) {
            int u = t*16 + m;
#pragma unroll
            for (int r = 0; r < 4; ++r) {
                float v = acc[g][t][r] + be2[t];
                sW[(g*16 + kc*4 + r)*136 + 64 + u] = f2bf(v);
            }
        }

    // ---- GEMM3: [h_row|ea_new][*,128] @ nW1; persist ea_new to global ----
    const u16* wp3 = wp + 32*512;
#pragma unroll
    for (int g = 0; g < 2; ++g)
#pragma unroll
        for (int t = 0; t < 4; ++t) acc[g][t] = z;
#pragma unroll
    for (int s = 0; s < 4; ++s) {
        s8v a[2];
#pragma unroll
        for (int g = 0; g < 2; ++g) {
            if (s < 2) {
                a[g] = *(const s8v*)(h_bf + (size_t)rowI[g]*64 + s*32 + kc*8);
            } else {
                a[g] = *(const s8v*)&sW[(g*16 + m)*136 + 64 + (s-2)*32 + kc*8];
                // coalesced write-back of ea_new for the next layer (A-layout regs)
                *(s8v*)(ea_bf + (e0 + wb + g*16 + m)*64 + (s-2)*32 + kc*8) = a[g];
            }
        }
#pragma unroll
        for (int t = 0; t < 4; ++t) {
            s8v bf = *(const s8v*)(wp3 + ((size_t)(s*4+t)*64 + L)*8);
            acc[0][t] = __builtin_amdgcn_mfma_f32_16x16x32_bf16(a[0], bf, acc[0][t], 0, 0, 0);
            acc[1][t] = __builtin_amdgcn_mfma_f32_16x16x32_bf16(a[1], bf, acc[1][t], 0, 0, 0);
        }
    }
    // relu -> t2 into LDS cols 0..63 (t1 dead)
#pragma unroll
    for (int g = 0; g < 2; ++g)
#pragma unroll
        for (int t = 0; t < 4; ++t) {
            int u = t*16 + m;
#pragma unroll
            for (int r = 0; r < 4; ++r) {
                float v = acc[g][t][r] + bn1[t];
                v = v > 0.f ? v : 0.f;
                sW[(g*16 + kc*4 + r)*136 + u] = f2bf(v);
            }
        }

    // ---- GEMM4: t2 @ nW2 -> msg; scatter-add ----
    const u16* wp4 = wp + 48*512;
#pragma unroll
    for (int g = 0; g < 2; ++g)
#pragma unroll
        for (int t = 0; t < 4; ++t) acc[g][t] = z;
#pragma unroll
    for (int s = 0; s < 2; ++s) {
        s8v a0 = *(const s8v*)&sW[(m)*136 + s*32 + kc*8];
        s8v a1 = *(const s8v*)&sW[(16 + m)*136 + s*32 + kc*8];
#pragma unroll
        for (int t = 0; t < 4; ++t) {
            s8v bf = *(const s8v*)(wp4 + ((size_t)(s*4+t)*64 + L)*8);
            acc[0][t] = __builtin_amdgcn_mfma_f32_16x16x32_bf16(a0, bf, acc[0][t], 0, 0, 0);
            acc[1][t] = __builtin_amdgcn_mfma_f32_16x16x32_bf16(a1, bf, acc[1][t], 0, 0, 0);
        }
    }
#pragma unroll
    for (int g = 0; g < 2; ++g)
#pragma unroll
        for (int r = 0; r < 4; ++r) {
            int nd = ei[(size_t)NE + e0 + wb + g*16 + kc*4 + r];
            float* dst = agg + (size_t)nd*64 + m;
#pragma unroll
            for (int t = 0; t < 4; ++t)
                unsafeAtomicAdd(dst + t*16, acc[g][t][r] + bn2[t]);
        }
}

// ---------------- h = relu(agg + h); refresh bf16 copy; re-zero agg ------------
__global__ void update_h(float* __restrict__ h, float* __restrict__ agg,
                         u16* __restrict__ h_bf, int zero_agg) {
    int i = (blockIdx.x * 256 + threadIdx.x) * 4;
    float4 a = *(const float4*)(agg + i);
    float4 hv = *(const float4*)(h + i);
    float4 v;
    v.x = fmaxf(a.x + hv.x, 0.f);
    v.y = fmaxf(a.y + hv.y, 0.f);
    v.z = fmaxf(a.z + hv.z, 0.f);
    v.w = fmaxf(a.w + hv.w, 0.f);
    *(float4*)(h + i) = v;
    *(uint2*)(h_bf + i) = make_uint2(pk2(v.x, v.y), pk2(v.z, v.w));
    if (zero_agg) *(float4*)(agg + i) = make_float4(0.f, 0.f, 0.f, 0.f);
}

// ---------------- mean pool ----------------------------------------------------
__global__ void pool1(const float* __restrict__ h, float* __restrict__ pooled) {
    float acc = 0.f;
    const int stride = gridDim.x * 256;
    for (int i = blockIdx.x * 256 + threadIdx.x; i < NN*64; i += stride)
        acc += h[i];
    __shared__ float sp[256];
    sp[threadIdx.x] = acc;
    __syncthreads();
    if (threadIdx.x < 64) {
        float v = sp[threadIdx.x] + sp[threadIdx.x+64] + sp[threadIdx.x+128] + sp[threadIdx.x+192];
        unsafeAtomicAdd(&pooled[threadIdx.x], v);
    }
}

__global__ void pool2(const float* __restrict__ pooled, const float* __restrict__ lW,
                      const float* __restrict__ lb, float* __restrict__ out) {
    int k = threadIdx.x;   // 64 threads
    float v = pooled[k] * (1.0f / NN);
#pragma unroll
    for (int o = 0; o < 3; ++o) {
        float p = v * lW[k*3 + o];
        for (int off = 32; off > 0; off >>= 1)
            p += __shfl_down(p, off);
        if (k == 0) out[o] = p + lb[o];
    }
}

extern "C" void kernel_launch(void* const* d_in, const int* in_sizes, int n_in,
                              void* d_out, int out_size, void* d_ws, size_t ws_size,
                              hipStream_t stream) {
    const float* x         = (const float*)d_in[0];
    const int*   ei        = (const int*)d_in[1];
    const float* edge_attr = (const float*)d_in[2];
    const float* pW        = (const float*)d_in[3];
    const float* pb        = (const float*)d_in[4];
    const float* eW1       = (const float*)d_in[5];
    const float* eb1       = (const float*)d_in[6];
    const float* eW2       = (const float*)d_in[7];
    const float* eb2       = (const float*)d_in[8];
    const float* nW1       = (const float*)d_in[9];
    const float* nb1       = (const float*)d_in[10];
    const float* nW2       = (const float*)d_in[11];
    const float* nb2       = (const float*)d_in[12];
    const float* lW        = (const float*)d_in[13];
    const float* lb        = (const float*)d_in[14];
    float* out = (float*)d_out;

    char* ws = (char*)d_ws;
    float* h     = (float*)(ws);                         // 25,600,000 B
    float* agg   = (float*)(ws + 25600000);              // 25,600,000 B
    u16*   h_bf  = (u16*)  (ws + 51200000);              // 12,800,000 B
    u16*   ea_bf = (u16*)  (ws + 64000000);              // 204,800,000 B
    u16*   wpack = (u16*)  (ws + 268800000);             // 188,416 B
    float* pooled= (float*)(ws + 268988416);             // 256 B

    pack_weights<<<184, 64, 0, stream>>>(pW, eW1, eW2, nW1, nW2, wpack);
    node_proj<<<(NN + 63)/64, 256, 0, stream>>>(x, pb, wpack, h, h_bf);
    cvt_ea<<<NE*64/(8*256), 256, 0, stream>>>(edge_attr, ea_bf);
    hipMemsetAsync(agg, 0, (size_t)NN*64*4, stream);
    for (int l = 0; l < 3; ++l) {
        edge_layer<<<NE/128, 256, 0, stream>>>(ei, h_bf, ea_bf,
                                               wpack + (16 + l*56)*512,
                                               eb1 + l*64, eb2 + l*64, nb1 + l*64, nb2 + l*64,
                                               agg);
        update_h<<<NN*64/4/256, 256, 0, stream>>>(h, agg, h_bf, l < 2 ? 1 : 0);
    }
    hipMemsetAsync(pooled, 0, 64*4, stream);
    pool1<<<256, 256, 0, stream>>>(h, pooled);
    pool2<<<1, 64, 0, stream>>>(pooled, lW, lb, out);
}

// Round 4
// 1730.307 us; speedup vs baseline: 2.1663x; 1.1279x over previous
//
#include <hip/hip_runtime.h>

#define NN 100000
#define NE 1600000
#define BINS_PAD 100352   // 98 * 1024 >= NN

typedef short s8v __attribute__((ext_vector_type(8)));
typedef float f32x4 __attribute__((ext_vector_type(4)));
typedef unsigned short u16;

__device__ __forceinline__ u16 f2bf(float f) {
    union { float f; unsigned u; } v; v.f = f;
    unsigned r = v.u + 0x7FFFu + ((v.u >> 16) & 1u);
    return (u16)(r >> 16);
}
__device__ __forceinline__ unsigned pk2(float a, float b) {
    return (unsigned)f2bf(a) | ((unsigned)f2bf(b) << 16);
}

// ---------------- weight fragment packing (bf16, B-operand layout) -------------
__global__ void pack_weights(const float* __restrict__ pW,
                             const float* __restrict__ eW1, const float* __restrict__ eW2,
                             const float* __restrict__ nW1, const float* __restrict__ nW2,
                             u16* __restrict__ wpack) {
    int b = blockIdx.x, L = threadIdx.x;
    const float* src; int s, t;
    if (b < 16) { src = pW; s = b >> 2; t = b & 3; }
    else {
        int bb = b - 16, l = bb / 56, r = bb % 56;
        if (r < 24)      {            src = eW1 + l*192*64; s = r>>2; t = r&3; }
        else if (r < 32) { r -= 24;   src = eW2 + l*64*64;  s = r>>2; t = r&3; }
        else if (r < 48) { r -= 32;   src = nW1 + l*128*64; s = r>>2; t = r&3; }
        else             { r -= 48;   src = nW2 + l*64*64;  s = r>>2; t = r&3; }
    }
    int kbase = s*32 + (L>>4)*8;
    int n = t*16 + (L&15);
    u16* dst = wpack + (size_t)b*512 + (size_t)L*8;
#pragma unroll
    for (int j = 0; j < 8; ++j) dst[j] = f2bf(src[(kbase+j)*64 + n]);
}

// ---------------- counting sort of edges by col --------------------------------
__global__ void k_hist(const int* __restrict__ ei, int* __restrict__ hist) {
    int e = blockIdx.x * 256 + threadIdx.x;
    atomicAdd(&hist[ei[(size_t)NE + e]], 1);
}

__global__ void k_scan1(const int* __restrict__ hist, int* __restrict__ cursor,
                        int* __restrict__ blockSums) {
    __shared__ int sS[256];
    int t = threadIdx.x, b = blockIdx.x;
    int base = b*1024 + t*4;
    int v0 = hist[base], v1 = hist[base+1], v2 = hist[base+2], v3 = hist[base+3];
    int s4 = v0 + v1 + v2 + v3;
    sS[t] = s4; __syncthreads();
    for (int off = 1; off < 256; off <<= 1) {
        int x = (t >= off) ? sS[t-off] : 0;
        __syncthreads();
        sS[t] += x;
        __syncthreads();
    }
    int excl = sS[t] - s4;
    cursor[base] = excl; cursor[base+1] = excl+v0;
    cursor[base+2] = excl+v0+v1; cursor[base+3] = excl+v0+v1+v2;
    if (t == 255) blockSums[b] = sS[255];
}

__global__ void k_scan2(int* __restrict__ blockSums) {
    __shared__ int sS[128];
    int t = threadIdx.x;
    int v = (t < 98) ? blockSums[t] : 0;
    sS[t] = v; __syncthreads();
    for (int off = 1; off < 128; off <<= 1) {
        int x = (t >= off) ? sS[t-off] : 0;
        __syncthreads();
        sS[t] += x;
        __syncthreads();
    }
    if (t < 98) blockSums[t] = sS[t] - v;   // exclusive
}

__global__ void k_scan3(int* __restrict__ cursor, const int* __restrict__ blockSums) {
    int i = blockIdx.x*1024 + threadIdx.x*4;
    int add = blockSums[blockIdx.x];
    cursor[i] += add; cursor[i+1] += add; cursor[i+2] += add; cursor[i+3] += add;
}

__global__ void k_scatter(const int* __restrict__ ei, int* __restrict__ cursor,
                          int* __restrict__ rowP, int* __restrict__ colP,
                          int* __restrict__ pos) {
    int e = blockIdx.x * 256 + threadIdx.x;
    int c = ei[(size_t)NE + e];
    int p = atomicAdd(&cursor[c], 1);
    rowP[p] = ei[e];
    colP[p] = c;
    pos[e] = p;
}

// permute edge_attr into sorted order + convert to bf16 (fused)
__global__ void k_permute_ea(const float* __restrict__ ea, const int* __restrict__ pos,
                             u16* __restrict__ eaP) {
    int g = threadIdx.x >> 6, lane = threadIdx.x & 63;
    int e = blockIdx.x * 4 + g;
    int p = pos[e];
    eaP[(size_t)p*64 + lane] = f2bf(ea[(size_t)e*64 + lane]);
}

// ---------------- node projection: h = x @ pW + pb -----------------------------
__global__ __launch_bounds__(256) void node_proj(const float* __restrict__ x,
                                                 const float* __restrict__ pb,
                                                 const u16* __restrict__ wpack,
                                                 float* __restrict__ h,
                                                 u16* __restrict__ h_bf) {
    __shared__ __align__(16) u16 sX[64*136];
    const int tid = threadIdx.x;
    const int n0 = blockIdx.x * 64;
    for (int i = tid; i < 64*32; i += 256) {
        int node = i >> 5, c = i & 31;
        float4 v = make_float4(0.f, 0.f, 0.f, 0.f);
        if (n0 + node < NN) v = *(const float4*)(x + (size_t)(n0+node)*128 + c*4);
        *(uint2*)&sX[node*136 + c*4] = make_uint2(pk2(v.x, v.y), pk2(v.z, v.w));
    }
    __syncthreads();
    const int w = tid >> 6, L = tid & 63;
    const int m = L & 15, kc = L >> 4;
    const int wb = w * 16;
    const f32x4 z = {0.f, 0.f, 0.f, 0.f};
    f32x4 acc[4] = {z, z, z, z};
#pragma unroll
    for (int s = 0; s < 4; ++s) {
        s8v a = *(const s8v*)&sX[(wb+m)*136 + s*32 + kc*8];
#pragma unroll
        for (int t = 0; t < 4; ++t) {
            s8v bf = *(const s8v*)(wpack + ((size_t)(s*4+t)*64 + L)*8);
            acc[t] = __builtin_amdgcn_mfma_f32_16x16x32_bf16(a, bf, acc[t], 0, 0, 0);
        }
    }
#pragma unroll
    for (int t = 0; t < 4; ++t) {
        int u = t*16 + m;
        float bias = pb[u];
#pragma unroll
        for (int r = 0; r < 4; ++r) {
            int node = n0 + wb + kc*4 + r;
            if (node < NN) {
                float v = acc[t][r] + bias;
                h[(size_t)node*64 + u] = v;
                h_bf[(size_t)node*64 + u] = f2bf(v);
            }
        }
    }
}

// ---------------- fused per-layer edge kernel (sorted edges) -------------------
// 4 waves x 32 edges; edges sorted by col. A-operands direct from global; LDS
// holds wave-private C->A transposes; after GEMM4 the same LDS is overlaid with
// an f32 msg buffer (stride 66, conflict-free) and a segmented reduction issues
// ONE atomic row per distinct node per tile (~9 vs 128).
__global__ __launch_bounds__(256, 4) void edge_layer(const int* __restrict__ rowP,
                                                     const int* __restrict__ colP,
                                                     const u16* __restrict__ h_bf,
                                                     u16* __restrict__ ea_bf,
                                                     const u16* __restrict__ wp,
                                                     const float* __restrict__ eb1,
                                                     const float* __restrict__ eb2,
                                                     const float* __restrict__ nb1,
                                                     const float* __restrict__ nb2,
                                                     float* __restrict__ agg) {
    __shared__ __align__(16) u16 sB[4*32*136];   // 34,816 B; msg overlay f32[128][66]
    __shared__ int sColP[128];
    __shared__ int sSeg[130];
    __shared__ int sCnt0, sK;
    float* msg = (float*)sB;
    const int tid = threadIdx.x;
    const int w = tid >> 6, L = tid & 63;
    const int m = L & 15, kc = L >> 4;
    const int wb = w * 32;
    const size_t e0 = (size_t)blockIdx.x * 128;
    u16* sW = sB + w * 32 * 136;

    // segment list from sorted cols
    if (tid < 128) sColP[tid] = colP[e0 + tid];
    __syncthreads();
    bool st = false;
    if (tid < 128) st = (tid == 0) || (sColP[tid] != sColP[tid-1]);
    unsigned long long mask = __ballot(st);
    if (tid == 0) sCnt0 = __popcll(mask);
    __syncthreads();
    if (st) {
        int base = (tid >= 64) ? sCnt0 : 0;
        int idx = base + __popcll(mask & ((1ull << (tid & 63)) - 1ull));
        sSeg[idx] = tid;
    }
    if (tid == 64) { int k = sCnt0 + __popcll(mask); sK = k; sSeg[k] = 128; }
    // sSeg/sK consumed after the post-msg barrier below

    float be1[4], be2[4], bn1[4], bn2[4];
#pragma unroll
    for (int t = 0; t < 4; ++t) {
        int u = t*16 + m;
        be1[t] = eb1[u]; be2[t] = eb2[u]; bn1[t] = nb1[u]; bn2[t] = nb2[u];
    }
    int rowI[2], colI[2];
#pragma unroll
    for (int g = 0; g < 2; ++g) {
        rowI[g] = rowP[e0 + wb + g*16 + m];
        colI[g] = sColP[wb + g*16 + m];
    }

    const f32x4 z = {0.f, 0.f, 0.f, 0.f};
    f32x4 acc[2][4];

    // ---- GEMM1: [h_row|h_col|ea][*,192] @ eW1 ----
#pragma unroll
    for (int g = 0; g < 2; ++g)
#pragma unroll
        for (int t = 0; t < 4; ++t) acc[g][t] = z;
#pragma unroll
    for (int s = 0; s < 6; ++s) {
        s8v a[2];
#pragma unroll
        for (int g = 0; g < 2; ++g) {
            if (s < 2)
                a[g] = *(const s8v*)(h_bf + (size_t)rowI[g]*64 + s*32 + kc*8);
            else if (s < 4)
                a[g] = *(const s8v*)(h_bf + (size_t)colI[g]*64 + (s-2)*32 + kc*8);
            else
                a[g] = *(const s8v*)(ea_bf + (e0 + wb + g*16 + m)*64 + (s-4)*32 + kc*8);
        }
#pragma unroll
        for (int t = 0; t < 4; ++t) {
            s8v bf = *(const s8v*)(wp + ((size_t)(s*4+t)*64 + L)*8);
            acc[0][t] = __builtin_amdgcn_mfma_f32_16x16x32_bf16(a[0], bf, acc[0][t], 0, 0, 0);
            acc[1][t] = __builtin_amdgcn_mfma_f32_16x16x32_bf16(a[1], bf, acc[1][t], 0, 0, 0);
        }
    }
#pragma unroll
    for (int g = 0; g < 2; ++g)
#pragma unroll
        for (int t = 0; t < 4; ++t) {
            int u = t*16 + m;
#pragma unroll
            for (int r = 0; r < 4; ++r) {
                float v = acc[g][t][r] + be1[t];
                v = v > 0.f ? v : 0.f;
                sW[(g*16 + kc*4 + r)*136 + u] = f2bf(v);
            }
        }

    // ---- GEMM2: t1 @ eW2 -> ea_new ----
    const u16* wp2 = wp + 24*512;
#pragma unroll
    for (int g = 0; g < 2; ++g)
#pragma unroll
        for (int t = 0; t < 4; ++t) acc[g][t] = z;
#pragma unroll
    for (int s = 0; s < 2; ++s) {
        s8v a0 = *(const s8v*)&sW[(m)*136 + s*32 + kc*8];
        s8v a1 = *(const s8v*)&sW[(16 + m)*136 + s*32 + kc*8];
#pragma unroll
        for (int t = 0; t < 4; ++t) {
            s8v bf = *(const s8v*)(wp2 + ((size_t)(s*4+t)*64 + L)*8);
            acc[0][t] = __builtin_amdgcn_mfma_f32_16x16x32_bf16(a0, bf, acc[0][t], 0, 0, 0);
            acc[1][t] = __builtin_amdgcn_mfma_f32_16x16x32_bf16(a1, bf, acc[1][t], 0, 0, 0);
        }
    }
#pragma unroll
    for (int g = 0; g < 2; ++g)
#pragma unroll
        for (int t = 0; t < 4; ++t) {
            int u = t*16 + m;
#pragma unroll
            for (int r = 0; r < 4; ++r) {
                float v = acc[g][t][r] + be2[t];
                sW[(g*16 + kc*4 + r)*136 + 64 + u] = f2bf(v);
            }
        }

    // ---- GEMM3: [h_row|ea_new][*,128] @ nW1; persist ea_new ----
    const u16* wp3 = wp + 32*512;
#pragma unroll
    for (int g = 0; g < 2; ++g)
#pragma unroll
        for (int t = 0; t < 4; ++t) acc[g][t] = z;
#pragma unroll
    for (int s = 0; s < 4; ++s) {
        s8v a[2];
#pragma unroll
        for (int g = 0; g < 2; ++g) {
            if (s < 2) {
                a[g] = *(const s8v*)(h_bf + (size_t)rowI[g]*64 + s*32 + kc*8);
            } else {
                a[g] = *(const s8v*)&sW[(g*16 + m)*136 + 64 + (s-2)*32 + kc*8];
                *(s8v*)(ea_bf + (e0 + wb + g*16 + m)*64 + (s-2)*32 + kc*8) = a[g];
            }
        }
#pragma unroll
        for (int t = 0; t < 4; ++t) {
            s8v bf = *(const s8v*)(wp3 + ((size_t)(s*4+t)*64 + L)*8);
            acc[0][t] = __builtin_amdgcn_mfma_f32_16x16x32_bf16(a[0], bf, acc[0][t], 0, 0, 0);
            acc[1][t] = __builtin_amdgcn_mfma_f32_16x16x32_bf16(a[1], bf, acc[1][t], 0, 0, 0);
        }
    }
#pragma unroll
    for (int g = 0; g < 2; ++g)
#pragma unroll
        for (int t = 0; t < 4; ++t) {
            int u = t*16 + m;
#pragma unroll
            for (int r = 0; r < 4; ++r) {
                float v = acc[g][t][r] + bn1[t];
                v = v > 0.f ? v : 0.f;
                sW[(g*16 + kc*4 + r)*136 + u] = f2bf(v);
            }
        }

    // ---- GEMM4: t2 @ nW2 -> msg ----
    const u16* wp4 = wp + 48*512;
#pragma unroll
    for (int g = 0; g < 2; ++g)
#pragma unroll
        for (int t = 0; t < 4; ++t) acc[g][t] = z;
#pragma unroll
    for (int s = 0; s < 2; ++s) {
        s8v a0 = *(const s8v*)&sW[(m)*136 + s*32 + kc*8];
        s8v a1 = *(const s8v*)&sW[(16 + m)*136 + s*32 + kc*8];
#pragma unroll
        for (int t = 0; t < 4; ++t) {
            s8v bf = *(const s8v*)(wp4 + ((size_t)(s*4+t)*64 + L)*8);
            acc[0][t] = __builtin_amdgcn_mfma_f32_16x16x32_bf16(a0, bf, acc[0][t], 0, 0, 0);
            acc[1][t] = __builtin_amdgcn_mfma_f32_16x16x32_bf16(a1, bf, acc[1][t], 0, 0, 0);
        }
    }

    __syncthreads();   // all waves done reading their LDS -> msg overlay is safe
#pragma unroll
    for (int g = 0; g < 2; ++g)
#pragma unroll
        for (int t = 0; t < 4; ++t) {
#pragma unroll
            for (int r = 0; r < 4; ++r) {
                int er = wb + g*16 + kc*4 + r;
                msg[er*66 + t*16 + m] = acc[g][t][r] + bn2[t];
            }
        }
    __syncthreads();   // msg visible

    // segmented reduction: one atomic row per distinct node per tile
    int k = sK;
    for (int s = w; s < k; s += 4) {
        int beg = sSeg[s], end = sSeg[s+1];
        int node = sColP[beg];
        float sum = 0.f;
        for (int e = beg; e < end; ++e) sum += msg[e*66 + L];
        unsafeAtomicAdd(&agg[(size_t)node*64 + L], sum);
    }
}

// ---------------- h = relu(agg + h); refresh bf16 copy; re-zero agg ------------
__global__ void update_h(float* __restrict__ h, float* __restrict__ agg,
                         u16* __restrict__ h_bf, int zero_agg) {
    int i = (blockIdx.x * 256 + threadIdx.x) * 4;
    float4 a = *(const float4*)(agg + i);
    float4 hv = *(const float4*)(h + i);
    float4 v;
    v.x = fmaxf(a.x + hv.x, 0.f);
    v.y = fmaxf(a.y + hv.y, 0.f);
    v.z = fmaxf(a.z + hv.z, 0.f);
    v.w = fmaxf(a.w + hv.w, 0.f);
    *(float4*)(h + i) = v;
    *(uint2*)(h_bf + i) = make_uint2(pk2(v.x, v.y), pk2(v.z, v.w));
    if (zero_agg) *(float4*)(agg + i) = make_float4(0.f, 0.f, 0.f, 0.f);
}

// ---------------- mean pool ----------------------------------------------------
__global__ void pool1(const float* __restrict__ h, float* __restrict__ pooled) {
    float acc = 0.f;
    const int stride = gridDim.x * 256;
    for (int i = blockIdx.x * 256 + threadIdx.x; i < NN*64; i += stride)
        acc += h[i];
    __shared__ float sp[256];
    sp[threadIdx.x] = acc;
    __syncthreads();
    if (threadIdx.x < 64) {
        float v = sp[threadIdx.x] + sp[threadIdx.x+64] + sp[threadIdx.x+128] + sp[threadIdx.x+192];
        unsafeAtomicAdd(&pooled[threadIdx.x], v);
    }
}

__global__ void pool2(const float* __restrict__ pooled, const float* __restrict__ lW,
                      const float* __restrict__ lb, float* __restrict__ out) {
    int k = threadIdx.x;   // 64 threads
    float v = pooled[k] * (1.0f / NN);
#pragma unroll
    for (int o = 0; o < 3; ++o) {
        float p = v * lW[k*3 + o];
        for (int off = 32; off > 0; off >>= 1)
            p += __shfl_down(p, off);
        if (k == 0) out[o] = p + lb[o];
    }
}

extern "C" void kernel_launch(void* const* d_in, const int* in_sizes, int n_in,
                              void* d_out, int out_size, void* d_ws, size_t ws_size,
                              hipStream_t stream) {
    const float* x         = (const float*)d_in[0];
    const int*   ei        = (const int*)d_in[1];
    const float* edge_attr = (const float*)d_in[2];
    const float* pW        = (const float*)d_in[3];
    const float* pb        = (const float*)d_in[4];
    const float* eW1       = (const float*)d_in[5];
    const float* eb1       = (const float*)d_in[6];
    const float* eW2       = (const float*)d_in[7];
    const float* eb2       = (const float*)d_in[8];
    const float* nW1       = (const float*)d_in[9];
    const float* nb1       = (const float*)d_in[10];
    const float* nW2       = (const float*)d_in[11];
    const float* nb2       = (const float*)d_in[12];
    const float* lW        = (const float*)d_in[13];
    const float* lb        = (const float*)d_in[14];
    float* out = (float*)d_out;

    char* ws = (char*)d_ws;
    float* h     = (float*)(ws);                         // 25,600,000 B
    float* agg   = (float*)(ws + 25600000);              // 25,600,000 B
    u16*   h_bf  = (u16*)  (ws + 51200000);              // 12,800,000 B
    u16*   eaP   = (u16*)  (ws + 64000000);              // 204,800,000 B (sorted-order ea)
    u16*   wpack = (u16*)  (ws + 268800000);             // 188,416 B
    float* pooled= (float*)(ws + 268988416);             // 256 B
    int*   rowP  = (int*)  (ws + 268988672);             // 6,400,000 B
    int*   colP  = (int*)  (ws + 275388672);             // 6,400,000 B  (ends 281,788,672)
    // sort scratch overlaid on agg (dead until after preprocessing):
    int* hist      = (int*)agg;                          // BINS_PAD ints
    int* cursor    = hist + BINS_PAD;                    // BINS_PAD ints
    int* blockSums = cursor + BINS_PAD;                  // 128 ints
    int* pos       = blockSums + 128;                    // NE ints (~7.2 MB total < 25.6 MB)

    // ---- counting sort by col (once; reused by all 3 layers) ----
    hipMemsetAsync(hist, 0, BINS_PAD*4, stream);
    k_hist<<<NE/256, 256, 0, stream>>>(ei, hist);
    k_scan1<<<98, 256, 0, stream>>>(hist, cursor, blockSums);
    k_scan2<<<1, 128, 0, stream>>>(blockSums);
    k_scan3<<<98, 256, 0, stream>>>(cursor, blockSums);
    k_scatter<<<NE/256, 256, 0, stream>>>(ei, cursor, rowP, colP, pos);
    k_permute_ea<<<NE/4, 256, 0, stream>>>(edge_attr, pos, eaP);

    pack_weights<<<184, 64, 0, stream>>>(pW, eW1, eW2, nW1, nW2, wpack);
    node_proj<<<(NN + 63)/64, 256, 0, stream>>>(x, pb, wpack, h, h_bf);

    hipMemsetAsync(agg, 0, (size_t)NN*64*4, stream);     // clobbers sort scratch (dead)
    for (int l = 0; l < 3; ++l) {
        edge_layer<<<NE/128, 256, 0, stream>>>(rowP, colP, h_bf, eaP,
                                               wpack + (16 + l*56)*512,
                                               eb1 + l*64, eb2 + l*64, nb1 + l*64, nb2 + l*64,
                                               agg);
        update_h<<<NN*64/4/256, 256, 0, stream>>>(h, agg, h_bf, l < 2 ? 1 : 0);
    }
    hipMemsetAsync(pooled, 0, 64*4, stream);
    pool1<<<256, 256, 0, stream>>>(h, pooled);
    pool2<<<1, 64, 0, stream>>>(pooled, lW, lb, out);
}